// Round 10
// baseline (278.198 us; speedup 1.0000x reference)
//
#include <hip/hip_runtime.h>

#define EPSBN 1e-5f
#define BCAP 12288      // entries per window bucket
#define CSRL_CAP 13312  // LDS csr staging cap
#define OVCAP 262144    // overflow entries
#define INS_CAP 24      // per-block per-bin LDS insert cap
#define INS_STRIDE 25   // LDS row stride (gcd(25,32)=1 -> bank spread)

#if defined(__has_builtin)
#if __has_builtin(__builtin_amdgcn_cvt_pk_f32_fp8) && __has_builtin(__builtin_amdgcn_cvt_pk_fp8_f32)
#define HAS_CVT_FP8 1
#endif
#endif

typedef float v2f_t __attribute__((ext_vector_type(2)));
typedef __attribute__((ext_vector_type(8))) short bf16x8;   // 8 bf16 = 4 VGPRs
typedef __attribute__((ext_vector_type(4))) float f32x4;

__device__ inline unsigned short f2bf(float f) {   // RNE float->bf16
    unsigned int u = __float_as_uint(f);
    u += 0x7fffu + ((u >> 16) & 1u);
    return (unsigned short)(u >> 16);
}

__device__ inline float fp8_dec_byte(int b) {
    int s = (b >> 7) & 1, e = (b >> 3) & 15, m = b & 7;
    float v = (e == 0) ? ldexpf((float)m, -9) : ldexpf((float)(8 + m), e - 10);
    return s ? -v : v;
}
__device__ inline unsigned int fp8_enc(float x) {
    unsigned int u = __float_as_uint(x);
    unsigned int s = u >> 31;
    u &= 0x7fffffffu;
    float a = __uint_as_float(u);
    unsigned int code;
    if (a >= 0.015625f) {
        if (a > 448.0f) code = 0x7E;
        else {
            int exp = (int)(u >> 23) - 127;
            unsigned int mant = u & 0x7fffffu;
            unsigned int keep = mant >> 20;
            unsigned int rest = mant & 0xfffffu;
            code = ((unsigned int)(exp + 7) << 3) | keep;
            unsigned int rnd = (rest > 0x80000u) || (rest == 0x80000u && (code & 1));
            code += rnd;
            if (code > 0x7E) code = 0x7E;
        }
    } else {
        code = (unsigned int)(a * 512.0f + 0.5f);
    }
    return (s << 7) | code;
}

// decode 8 packed fp8 (uint2) into 8 floats
__device__ __forceinline__ void fp8x8_dec(uint2 w, float* v) {
#ifdef HAS_CVT_FP8
    v2f_t l0 = __builtin_amdgcn_cvt_pk_f32_fp8((int)w.x, false);
    v2f_t h0 = __builtin_amdgcn_cvt_pk_f32_fp8((int)w.x, true);
    v2f_t l1 = __builtin_amdgcn_cvt_pk_f32_fp8((int)w.y, false);
    v2f_t h1 = __builtin_amdgcn_cvt_pk_f32_fp8((int)w.y, true);
    v[0] = l0[0]; v[1] = l0[1]; v[2] = h0[0]; v[3] = h0[1];
    v[4] = l1[0]; v[5] = l1[1]; v[6] = h1[0]; v[7] = h1[1];
#else
    v[0] = fp8_dec_byte(w.x & 255);        v[1] = fp8_dec_byte((w.x >> 8) & 255);
    v[2] = fp8_dec_byte((w.x >> 16) & 255); v[3] = fp8_dec_byte(w.x >> 24);
    v[4] = fp8_dec_byte(w.y & 255);        v[5] = fp8_dec_byte((w.y >> 8) & 255);
    v[6] = fp8_dec_byte((w.y >> 16) & 255); v[7] = fp8_dec_byte(w.y >> 24);
#endif
}

// ------- setup: zero tails + graph bounds + BN fold + bf16 W-frag pack + pocket MLP/M -------
__global__ void setup_kernel(int* __restrict__ tails, int ntail,
                             const int* __restrict__ batch, int* __restrict__ gstart,
                             int n, int g,
                             const float* __restrict__ conv0_b, const float* __restrict__ convs_b,
                             const float* __restrict__ gamma, const float* __restrict__ beta,
                             const float* __restrict__ mean, const float* __restrict__ var,
                             float* __restrict__ sc, float* __restrict__ sh,
                             const float* __restrict__ convs_W, unsigned short* __restrict__ Wp,
                             const float* __restrict__ pf, const float* __restrict__ W1,
                             const float* __restrict__ b1, const float* __restrict__ W2,
                             const float* __restrict__ b2, const float* __restrict__ bilW,
                             float* __restrict__ M) {
    int t = threadIdx.x;
    int i = blockIdx.x * 256 + t;
    if (i < ntail * 32) tails[i] = 0;
    if (i < 384) {
        int l = i >> 7, f = i & 127;
        float bias = (l == 0) ? conv0_b[f] : convs_b[(l - 1) * 128 + f];
        float s = gamma[i] * rsqrtf(var[i] + EPSBN);
        sc[i] = s;
        sh[i] = fmaf(s, bias - mean[i], beta[i]);
    }
    // pack convs_W (2 layers of 128x128) into MFMA B-fragment order, bf16.
    // frag addr: ((kk*8 + nt)*64 + lane)*8 + j  ->  W[kk*32 + (lane>>4)*8 + j][nt*16 + (lane&15)]
    if (i < 32768) {
        int l = i >> 14;
        int fidx = i & 16383;
        int j  = fidx & 7;
        int ln = (fidx >> 3) & 63;
        int nt = (fidx >> 9) & 7;
        int kk = fidx >> 12;
        int k = kk * 32 + (ln >> 4) * 8 + j;
        int c = nt * 16 + (ln & 15);
        Wp[i] = f2bf(convs_W[l * 16384 + k * 128 + c]);
    }
    if (i < n) {
        int b = batch[i];
        int bp = (i == 0) ? -1 : batch[i - 1];
        for (int q = bp + 1; q <= b; ++q) gstart[q] = i;
        if (i == n - 1) {
            for (int q = b + 1; q <= g; ++q) gstart[q] = n;
        }
    }
    // absorbed pk_bilM (blocks 0..31 compute M = bilW . pk)
    if (blockIdx.x < 32) {
        __shared__ float h1s[64];
        __shared__ float spk[64];
        if (t < 64) {
            float acc = b1[t];
            #pragma unroll
            for (int k = 0; k < 28; ++k) acc = fmaf(pf[k], W1[k * 64 + t], acc);
            h1s[t] = fmaxf(acc, 0.f);
        }
        __syncthreads();
        if (t < 64) {
            float acc2 = b2[t];
            for (int k = 0; k < 64; ++k) acc2 = fmaf(h1s[k], W2[k * 64 + t], acc2);
            spk[t] = acc2;
        }
        __syncthreads();
        if (i < 64 * 128) {
            const float* wr = bilW + (size_t)i * 64;
            float acc = 0.f;
            #pragma unroll 8
            for (int j = 0; j < 64; ++j) acc = fmaf(wr[j], spk[j], acc);
            M[i] = acc;
        }
    }
}

// ---------------- bucket edges by dst window (d>>8) via LDS staging ----------------
__launch_bounds__(256)
__global__ void bucket_kernel(const int* __restrict__ src, const int* __restrict__ dst,
                              unsigned int* __restrict__ buckets, int* __restrict__ tails,
                              unsigned int* __restrict__ ovf, int e, int nwq) {
    __shared__ unsigned int buf[256 * INS_STRIDE];
    __shared__ int cnt[256];
    __shared__ int basee[256];
    int t = threadIdx.x;
    cnt[t] = 0;
    __syncthreads();
    int c0 = blockIdx.x * 2048;
    int c1 = min(c0 + 2048, e);
    for (int i = c0 + t; i < c1; i += 256) {
        int d = dst[i];
        int bb = d >> 8;
        unsigned int val = (unsigned int)src[i] | ((unsigned int)d << 16);
        int pos = atomicAdd(&cnt[bb], 1);
        if (pos < INS_CAP) buf[bb * INS_STRIDE + pos] = val;
        else {
            int op = atomicAdd(&tails[nwq * 32], 1);
            if (op < OVCAP) ovf[op] = val;
        }
    }
    __syncthreads();
    int lane = t & 63, wv = t >> 6;
    int bb0 = wv * 64;
    {
        int b = bb0 + lane;
        int c = (b < nwq) ? min(cnt[b], INS_CAP) : 0;
        basee[b] = c ? atomicAdd(&tails[b * 32], c) : 0;
    }
    for (int k = 0; k < 64; ++k) {
        int b = bb0 + k;
        if (b >= nwq) break;
        int c = min(cnt[b], INS_CAP);
        if (c == 0) continue;
        int g = basee[b];
        if (lane < c) {
            unsigned int v = buf[b * INS_STRIDE + lane];
            int gp = g + lane;
            if (gp < BCAP) buckets[(size_t)b * BCAP + gp] = v;
            else {
                int op = atomicAdd(&tails[nwq * 32], 1);
                if (op < OVCAP) ovf[op] = v;
            }
        }
    }
}

// ---------------- build CSR window-locally in LDS; coalesced write-out ----------------
// Also writes xs = dinv .* x  (pre-scaled node features for the layer-0 gather).
__launch_bounds__(256)
__global__ void build_csr(const unsigned int* __restrict__ buckets,
                          const int* __restrict__ tails, const unsigned int* __restrict__ ovf,
                          unsigned short* __restrict__ csr, int* __restrict__ deg,
                          int* __restrict__ offs, float* __restrict__ dinv,
                          const float* __restrict__ x, float* __restrict__ xs,
                          int n, int nwq) {
    __shared__ unsigned short csrL[CSRL_CAP];
    __shared__ int degL[256], curL[256], offsL[256], cntW[256];
    __shared__ int wsum4[4];
    __shared__ int wstart;
    int b = blockIdx.x, t = threadIdx.x;
    int lo = b << 8;
    int hi = min(lo + 256, n);
    int nw = hi - lo;
    int ovn = min(tails[nwq * 32], OVCAP);
    cntW[t] = (t < nwq) ? min(tails[t * 32], BCAP) : 0;
    degL[t] = 0;
    __syncthreads();
    for (int i = t; i < ovn; i += 256)
        atomicAdd(&cntW[(ovf[i] >> 16) >> 8], 1);
    __syncthreads();
    if (t == 0) {
        int s = 0;
        for (int w = 0; w < b; ++w) s += cntW[w];
        wstart = s;
    }
    int myvalid = min(tails[b * 32], BCAP);
    const unsigned int* myb = buckets + (size_t)b * BCAP;
    for (int i = t; i < myvalid; i += 256)
        atomicAdd(&degL[(myb[i] >> 16) & 255], 1);
    for (int i = t; i < ovn; i += 256) {
        unsigned int v = ovf[i];
        int d = v >> 16;
        if (d >= lo && d < hi) atomicAdd(&degL[d & 255], 1);
    }
    __syncthreads();
    {
        int lane = t & 63, wv = t >> 6;
        int v = degL[t];
        int sc0 = v;
        #pragma unroll
        for (int o = 1; o < 64; o <<= 1) {
            int u = __shfl_up(sc0, o);
            if (lane >= o) sc0 += u;
        }
        if (lane == 63) wsum4[wv] = sc0;
        __syncthreads();
        int wb = 0;
        for (int q = 0; q < wv; ++q) wb += wsum4[q];
        offsL[t] = wb + sc0 - v;
        curL[t] = offsL[t];
    }
    __syncthreads();
    for (int i = t; i < myvalid; i += 256) {
        unsigned int v = myb[i];
        int pos = atomicAdd(&curL[(v >> 16) & 255], 1);
        if (pos < CSRL_CAP) csrL[pos] = (unsigned short)(v & 0xffffu);
    }
    for (int i = t; i < ovn; i += 256) {
        unsigned int v = ovf[i];
        int d = v >> 16;
        if (d >= lo && d < hi) {
            int pos = atomicAdd(&curL[d & 255], 1);
            if (pos < CSRL_CAP) csrL[pos] = (unsigned short)(v & 0xffffu);
        }
    }
    __syncthreads();
    int base = wstart;
    int total = min(cntW[b], CSRL_CAP);
    for (int i = t; i < total; i += 256)
        csr[base + i] = csrL[i];
    if (t < nw) {
        int dgi = degL[t];
        deg[lo + t] = dgi;
        offs[lo + t] = base + offsL[t];
        float dv_ = rsqrtf((float)dgi + 1.0f);
        dinv[lo + t] = dv_;
        #pragma unroll
        for (int k = 0; k < 7; ++k)
            xs[(size_t)(lo + t) * 7 + k] = dv_ * x[(size_t)(lo + t) * 7 + k];
    }
}

// ------- fused dense 128->128 (MFMA bf16) + 8*dinv prescale + fp8-encode + store -------
// hL: [16][136] bf16 rows; Wp pre-packed B-fragments.
// Output row = 8*dinv[node]*(W.h)[node]; the x8 (exact pow2) keeps values in fp8
// normal range (consumer divides by 8).
__device__ __forceinline__ void dense_fp8_out(const unsigned short* hL,
                                              const unsigned short* __restrict__ Wp,
                                              const float* __restrict__ dinv,
                                              unsigned char* __restrict__ out8,
                                              int b0n, int n, int lane, int wv) {
    f32x4 acc0 = {0.f, 0.f, 0.f, 0.f};
    f32x4 acc1 = {0.f, 0.f, 0.f, 0.f};
    int r = lane & 15, g = lane >> 4;
    int nt0 = wv * 2, nt1 = nt0 + 1;
    #pragma unroll
    for (int kk = 0; kk < 4; ++kk) {
        bf16x8 a  = *(const bf16x8*)(hL + r * 136 + kk * 32 + g * 8);
        bf16x8 b0 = *(const bf16x8*)(Wp + ((kk * 8 + nt0) * 64 + lane) * 8);
        bf16x8 b1 = *(const bf16x8*)(Wp + ((kk * 8 + nt1) * 64 + lane) * 8);
        acc0 = __builtin_amdgcn_mfma_f32_16x16x32_bf16(a, b0, acc0, 0, 0, 0);
        acc1 = __builtin_amdgcn_mfma_f32_16x16x32_bf16(a, b1, acc1, 0, 0, 0);
    }
    #pragma unroll
    for (int j = 0; j < 4; ++j) {
        int node = b0n + g * 4 + j;
        if (node < n) {
            float dj = dinv[node] * 8.f;
            float s0 = acc0[j] * dj, s1 = acc1[j] * dj;
            unsigned char q0, q1;
#ifdef HAS_CVT_FP8
            q0 = (unsigned char)(__builtin_amdgcn_cvt_pk_fp8_f32(s0, s0, 0, false) & 0xff);
            q1 = (unsigned char)(__builtin_amdgcn_cvt_pk_fp8_f32(s1, s1, 0, false) & 0xff);
#else
            q0 = (unsigned char)fp8_enc(s0);
            q1 = (unsigned char)fp8_enc(s1);
#endif
            out8[(size_t)node * 128 + nt0 * 16 + r] = q0;
            out8[(size_t)node * 128 + nt1 * 16 + r] = q1;
        }
    }
}

// ------- fused layer-0: agg(xs) 7-dim + dense 7->128 + BN + relu + dense W1 -> fp8 -------
// Neighbor gather reads pre-scaled xs (= dinv.*x): no dinv gather, no weight shuffle.
__launch_bounds__(256)
__global__ void layer0f_kernel(const float* __restrict__ x, const float* __restrict__ xs,
                               const unsigned short* __restrict__ csr,
                               const int* __restrict__ offs, const int* __restrict__ degi,
                               const float* __restrict__ dinv, const float* __restrict__ W,
                               const float* __restrict__ sc, const float* __restrict__ sh,
                               const unsigned short* __restrict__ Wp,
                               unsigned char* __restrict__ out8, int n) {
    __shared__ float sW[7 * 128];
    __shared__ float ssc[128], ssh[128];
    __shared__ unsigned short hL[16 * 136];
    int t = threadIdx.x;
    for (int i = t; i < 7 * 128; i += 256) sW[i] = W[i];
    if (t < 128) { ssc[t] = sc[t]; ssh[t] = sh[t]; }
    __syncthreads();
    int lane = t & 63, wv = t >> 6;
    int b0n = blockIdx.x * 16;
    int e = lane >> 3, f = lane & 7;
    for (int nd = 0; nd < 4; ++nd) {
        int node = b0n + wv * 4 + nd;
        if (node < n) {
            int off = offs[node], cnt = degi[node];
            float di = dinv[node];
            float acc = 0.f, accB = 0.f;
            for (int b0 = 0; b0 < cnt; b0 += 64) {
                int j = b0 + lane;
                int s = 0;
                if (j < cnt) s = csr[off + j];
                int m = cnt - b0; if (m > 64) m = 64;
                int m16 = (m + 15) & ~15;
                for (int i2 = 0; i2 < m16; i2 += 16) {
                    int ss1 = __shfl(s, i2 + e);
                    int ss2 = __shfl(s, i2 + 8 + e);
                    float nn1 = (i2 + e < m) ? 1.f : 0.f;
                    float nn2 = (i2 + 8 + e < m) ? 1.f : 0.f;
                    float v1 = 0.f, v2 = 0.f;
                    if (f < 7) {
                        v1 = xs[(size_t)ss1 * 7 + f];
                        v2 = xs[(size_t)ss2 * 7 + f];
                    }
                    acc  = fmaf(nn1, v1, acc);
                    accB = fmaf(nn2, v2, accB);
                }
            }
            acc += accB;
            acc += __shfl_xor(acc, 8);
            acc += __shfl_xor(acc, 16);
            acc += __shfl_xor(acc, 32);
            float self = (f < 7) ? x[(size_t)node * 7 + f] : 0.f;
            float xa = di * (acc + di * self);
            float xk[7];
            #pragma unroll
            for (int k = 0; k < 7; ++k) xk[k] = __shfl(xa, k);
            int fo = lane * 2;
            float o0 = 0.f, o1 = 0.f;
            #pragma unroll
            for (int k = 0; k < 7; ++k) {
                o0 = fmaf(xk[k], sW[k * 128 + fo], o0);
                o1 = fmaf(xk[k], sW[k * 128 + fo + 1], o1);
            }
            o0 = fmaxf(fmaf(ssc[fo],     o0, ssh[fo]),     0.f);
            o1 = fmaxf(fmaf(ssc[fo + 1], o1, ssh[fo + 1]), 0.f);
            unsigned int p = (unsigned int)f2bf(o0) | ((unsigned int)f2bf(o1) << 16);
            *(unsigned int*)(&hL[(wv * 4 + nd) * 136 + fo]) = p;
        }
    }
    __syncthreads();
    dense_fp8_out(hL, Wp, dinv, out8, b0n, n, lane, wv);
}

// ------- fused aggregation over PRE-SCALED fp8 table + foldedBN + ReLU (+ dense -> fp8) -----
// Table rows are 8*dinv[s]*(W.h)[s]: aggregation = masked row-sum (no dinv gather).
// Self term: table[node] = 8*di*h[node]  =>  agg_total = (sum + table[node]) * di/8.
// TWO DEGREE-MATCHED NODES PER WAVE: the block's 16 nodes are ranked by degree
// (O(16^2) in LDS) and paired by adjacent rank, so the interleaved max(cntA,cntB)
// loop has ~2% padded slots instead of ~10%; pairs are dealt round-robin to waves
// (wave wv gets pairs wv and wv+4) to balance the pre-dense barrier.
// Per-node arithmetic order is unchanged (bitwise-identical results).
// DENSE=1: writes next layer's scaled fp8 table via MFMA; DENSE=0: writes bf16 h3.
template<int DENSE>
__launch_bounds__(256)
__global__ void aggf_kernel(const unsigned int* __restrict__ hw, const unsigned short* __restrict__ csr,
                            const int* __restrict__ offs, const int* __restrict__ degi,
                            const float* __restrict__ dinv,
                            const float* __restrict__ sc, const float* __restrict__ shv,
                            const unsigned short* __restrict__ Wp,
                            unsigned char* __restrict__ out8,
                            unsigned int* __restrict__ outH2, int n) {
    __shared__ unsigned short hL[16 * 136];
    __shared__ unsigned char prL[16];   // rank -> block-local node id
    int t = threadIdx.x, lane = t & 63, wv = t >> 6;
    int fl = lane & 15, grp = lane >> 4;
    int b0n = blockIdx.x * 16;
    // degree-rank the block's 16 nodes (invalid nodes sort first with deg -1)
    if (t < 16) {
        int node = b0n + t;
        int dt = (node < n) ? degi[node] : -1;
        int rank = 0;
        #pragma unroll
        for (int j = 0; j < 16; ++j) {
            int nj = b0n + j;
            int dj = (nj < n) ? degi[nj] : -1;
            rank += (dj < dt) || (dj == dt && j < t);
        }
        prL[rank] = (unsigned char)t;
    }
    __syncthreads();
    for (int np = 0; np < 2; ++np) {
        int pr = wv + np * 4;                 // wave wv handles pairs wv and wv+4
        int lidA = prL[pr * 2];
        int lidB = prL[pr * 2 + 1];
        int nodeA = b0n + lidA;
        int nodeB = b0n + lidB;
        bool okA = nodeA < n, okB = nodeB < n;
        int offA = okA ? offs[nodeA] : 0;
        int cntA = okA ? degi[nodeA] : 0;
        int offB = okB ? offs[nodeB] : 0;
        int cntB = okB ? degi[nodeB] : 0;
        float diA = okA ? dinv[nodeA] : 0.f;
        float diB = okB ? dinv[nodeB] : 0.f;
        float aA[8], aB[8];
        #pragma unroll
        for (int i = 0; i < 8; ++i) { aA[i] = 0.f; aB[i] = 0.f; }
        int cmax = max(cntA, cntB);
        for (int c0 = 0; c0 < cmax; c0 += 64) {
            int j = c0 + lane;
            int sA = (j < cntA) ? csr[offA + j] : 0;
            int sB = (j < cntB) ? csr[offB + j] : 0;
            int mA = cntA - c0; mA = (mA < 0) ? 0 : ((mA > 64) ? 64 : mA);
            int mB = cntB - c0; mB = (mB < 0) ? 0 : ((mB > 64) ? 64 : mB);
            int mm = (mA > mB) ? mA : mB;
            int m16 = (mm + 15) & ~15;
            for (int e = 0; e < m16; e += 16) {
                uint2 wA[4], wB[4];
                #pragma unroll
                for (int u = 0; u < 4; ++u) {
                    int jj = e + u * 4 + grp;
                    int ssA = __shfl(sA, jj);
                    int ssB = __shfl(sB, jj);
                    wA[u] = *(const uint2*)(hw + (size_t)ssA * 32 + fl * 2);
                    wB[u] = *(const uint2*)(hw + (size_t)ssB * 32 + fl * 2);
                }
                #pragma unroll
                for (int u = 0; u < 4; ++u) {
                    int jj = e + u * 4 + grp;
                    float nnA = (jj < mA) ? 1.f : 0.f;
                    float nnB = (jj < mB) ? 1.f : 0.f;
                    float v[8];
                    fp8x8_dec(wA[u], v);
                    #pragma unroll
                    for (int i = 0; i < 8; ++i) aA[i] = fmaf(nnA, v[i], aA[i]);
                    fp8x8_dec(wB[u], v);
                    #pragma unroll
                    for (int i = 0; i < 8; ++i) aB[i] = fmaf(nnB, v[i], aB[i]);
                }
            }
        }
        #pragma unroll
        for (int i = 0; i < 8; ++i) {
            aA[i] += __shfl_xor(aA[i], 16);
            aA[i] += __shfl_xor(aA[i], 32);
            aB[i] += __shfl_xor(aB[i], 16);
            aB[i] += __shfl_xor(aB[i], 32);
        }
        if (grp == 0) {
            #pragma unroll
            for (int half = 0; half < 2; ++half) {
                int node = (half == 0) ? nodeA : nodeB;
                int lid  = (half == 0) ? lidA : lidB;
                bool ok  = (half == 0) ? okA : okB;
                float di = (half == 0) ? diA : diB;
                float* a = (half == 0) ? aA : aB;
                if (ok) {
                    uint2 ws = *(const uint2*)(hw + (size_t)node * 32 + fl * 2);
                    float sv[8];
                    fp8x8_dec(ws, sv);
                    int f0 = fl * 8;
                    float dis = di * 0.125f;   // undo the x8 table prescale (exact pow2)
                    float vo[8];
                    #pragma unroll
                    for (int i = 0; i < 8; ++i) {
                        float vv = (a[i] + sv[i]) * dis;
                        vo[i] = fmaxf(fmaf(sc[f0 + i], vv, shv[f0 + i]), 0.f);
                    }
                    uint4 P;
                    P.x = (unsigned int)f2bf(vo[0]) | ((unsigned int)f2bf(vo[1]) << 16);
                    P.y = (unsigned int)f2bf(vo[2]) | ((unsigned int)f2bf(vo[3]) << 16);
                    P.z = (unsigned int)f2bf(vo[4]) | ((unsigned int)f2bf(vo[5]) << 16);
                    P.w = (unsigned int)f2bf(vo[6]) | ((unsigned int)f2bf(vo[7]) << 16);
                    if (DENSE) {
                        *(uint4*)(&hL[lid * 136 + f0]) = P;
                    } else {
                        *(uint4*)(outH2 + (size_t)node * 64 + fl * 4) = P;
                    }
                }
            }
        }
    }
    if (DENSE) {
        __syncthreads();
        dense_fp8_out(hL, Wp, dinv, out8, b0n, n, lane, wv);
    }
}

// ------- per-graph tail (segment-mean over bf16 h3 + bilinear + classifier), 256 thr -------
__launch_bounds__(256)
__global__ void final_kernel(const unsigned int* __restrict__ h2, const int* __restrict__ gstart,
                             const float* __restrict__ M, const float* __restrict__ bil_b,
                             const float* __restrict__ cW1, const float* __restrict__ cb1,
                             const float* __restrict__ cW2, const float* __restrict__ cb2,
                             float* __restrict__ out) {
    __shared__ float lig4[4][128];
    __shared__ float lig[128];
    __shared__ float inter[64];
    __shared__ float hc[32];
    int g = blockIdx.x, t = threadIdx.x;
    int grp = t >> 6, tid = t & 63;
    int s = gstart[g], e = gstart[g + 1];
    float a0 = 0.f, a1 = 0.f, b0 = 0.f, b1 = 0.f;
    int i = s + grp;
    for (; i + 4 < e; i += 8) {
        unsigned int u0 = h2[(size_t)i * 64 + tid];
        unsigned int u1 = h2[(size_t)(i + 4) * 64 + tid];
        a0 += __uint_as_float(u0 << 16);
        a1 += __uint_as_float(u0 & 0xffff0000u);
        b0 += __uint_as_float(u1 << 16);
        b1 += __uint_as_float(u1 & 0xffff0000u);
    }
    for (; i < e; i += 4) {
        unsigned int u0 = h2[(size_t)i * 64 + tid];
        a0 += __uint_as_float(u0 << 16);
        a1 += __uint_as_float(u0 & 0xffff0000u);
    }
    lig4[grp][tid * 2]     = a0 + b0;
    lig4[grp][tid * 2 + 1] = a1 + b1;
    __syncthreads();
    if (t < 128) {
        float c = (float)(e - s); if (c < 1.f) c = 1.f;
        lig[t] = ((lig4[0][t] + lig4[1][t]) + (lig4[2][t] + lig4[3][t])) / c;
    }
    __syncthreads();
    if (t < 64) {
        float acc = bil_b[t];
        const float* mr = M + (size_t)t * 128;
        #pragma unroll 8
        for (int k = 0; k < 128; ++k) acc = fmaf(lig[k], mr[k], acc);
        inter[t] = acc;
    }
    __syncthreads();
    if (t < 32) {
        float acc = cb1[t];
        #pragma unroll 8
        for (int o = 0; o < 64; ++o) acc = fmaf(inter[o], cW1[o * 32 + t], acc);
        hc[t] = fmaxf(acc, 0.f);
    }
    __syncthreads();
    if (t == 0) {
        float acc = cb2[0];
        #pragma unroll
        for (int j = 0; j < 32; ++j) acc = fmaf(hc[j], cW2[j], acc);
        out[g] = acc;
    }
}

extern "C" void kernel_launch(void* const* d_in, const int* in_sizes, int n_in,
                              void* d_out, int out_size, void* d_ws, size_t ws_size,
                              hipStream_t stream) {
    const float* x        = (const float*)d_in[0];
    const int*   edge     = (const int*)d_in[1];
    const int*   batch    = (const int*)d_in[2];
    const float* pocket   = (const float*)d_in[3];
    const float* conv0_W  = (const float*)d_in[4];
    const float* conv0_b  = (const float*)d_in[5];
    const float* convs_W  = (const float*)d_in[6];
    const float* convs_b  = (const float*)d_in[7];
    const float* bn_gamma = (const float*)d_in[8];
    const float* bn_beta  = (const float*)d_in[9];
    const float* bn_mean  = (const float*)d_in[10];
    const float* bn_var   = (const float*)d_in[11];
    const float* pmlp_W1  = (const float*)d_in[12];
    const float* pmlp_b1  = (const float*)d_in[13];
    const float* pmlp_W2  = (const float*)d_in[14];
    const float* pmlp_b2  = (const float*)d_in[15];
    const float* bil_W    = (const float*)d_in[16];
    const float* bil_b    = (const float*)d_in[17];
    const float* cls_W1   = (const float*)d_in[18];
    const float* cls_b1   = (const float*)d_in[19];
    const float* cls_W2   = (const float*)d_in[20];
    const float* cls_b2   = (const float*)d_in[21];

    const int N = in_sizes[0] / 7;
    const int E = in_sizes[1] / 2;
    const int G = out_size;
    const int* srcA = edge;
    const int* dstA = edge + E;
    const int NB  = (N + 255) / 256;
    const int NWQ = (N + 255) >> 8;
    const int NBL = (N + 15) / 16;

    char* p = (char*)d_ws;
    auto alloc = [&](size_t bytes) -> void* {
        void* r = (void*)p;
        p += (bytes + 255) & ~(size_t)255;
        return r;
    };
    int*   tails    = (int*)alloc((size_t)(NWQ + 1) * 32 * 4);
    unsigned int* buckets = (unsigned int*)alloc((size_t)NWQ * BCAP * 4);
    unsigned int* ovf     = (unsigned int*)alloc((size_t)OVCAP * 4);
    int*   deg      = (int*)alloc((size_t)N * 4);
    int*   offs     = (int*)alloc((size_t)N * 4);
    float* dinv     = (float*)alloc((size_t)N * 4);
    float* xs       = (float*)alloc((size_t)N * 7 * 4);
    unsigned short* csr = (unsigned short*)alloc((size_t)E * 2);
    unsigned char* bufH8a = (unsigned char*)alloc((size_t)N * 128);
    unsigned char* bufH8b = (unsigned char*)alloc((size_t)N * 128);
    unsigned int* bufH2 = (unsigned int*)alloc((size_t)N * 64 * 4);   // bf16 h3, 2 feats/uint
    int*   gstart   = (int*)alloc((size_t)(G + 1) * 4);
    float* M        = (float*)alloc(64 * 128 * 4);
    float* sc       = (float*)alloc(384 * 4);
    float* shv      = (float*)alloc(384 * 4);
    unsigned short* Wp = (unsigned short*)alloc((size_t)2 * 16384 * 2);

    setup_kernel<<<NB, 256, 0, stream>>>(tails, NWQ + 1, batch, gstart, N, G,
                                         conv0_b, convs_b, bn_gamma, bn_beta, bn_mean, bn_var,
                                         sc, shv, convs_W, Wp,
                                         pocket, pmlp_W1, pmlp_b1, pmlp_W2, pmlp_b2, bil_W, M);
    bucket_kernel<<<(E + 2047) / 2048, 256, 0, stream>>>(srcA, dstA, buckets, tails, ovf,
                                                         E, NWQ);
    build_csr<<<NWQ, 256, 0, stream>>>(buckets, tails, ovf, csr, deg, offs, dinv,
                                       x, xs, N, NWQ);

    // layer 0 fused: agg(xs) + W0 + BN + relu + W1(MFMA) -> scaled fp8 table1
    layer0f_kernel<<<NBL, 256, 0, stream>>>(x, xs, csr, offs, deg, dinv, conv0_W,
                                            sc, shv, Wp, bufH8a, N);
    // layer 1 fused: agg(table1) + BN + relu + W2(MFMA) -> scaled fp8 table2
    aggf_kernel<1><<<NBL, 256, 0, stream>>>((const unsigned int*)bufH8a, csr, offs, deg, dinv,
                                            sc + 128, shv + 128, Wp + 16384, bufH8b, nullptr, N);
    // layer 2: agg(table2) + BN + relu -> bf16 h3
    aggf_kernel<0><<<NBL, 256, 0, stream>>>((const unsigned int*)bufH8b, csr, offs, deg, dinv,
                                            sc + 256, shv + 256, nullptr, nullptr, bufH2, N);

    final_kernel<<<G, 256, 0, stream>>>(bufH2, gstart, M, bil_b, cls_W1, cls_b1, cls_W2, cls_b2,
                                        (float*)d_out);
}

// Round 11
// 272.258 us; speedup vs baseline: 1.0218x; 1.0218x over previous
//
#include <hip/hip_runtime.h>

#define EPSBN 1e-5f
#define BCAP 12288      // entries per window bucket
#define CSRL_CAP 13312  // LDS csr staging cap
#define OVCAP 262144    // overflow entries
#define INS_CAP 24      // per-block per-bin LDS insert cap
#define INS_STRIDE 25   // LDS row stride (gcd(25,32)=1 -> bank spread)

#if defined(__has_builtin)
#if __has_builtin(__builtin_amdgcn_cvt_pk_f32_fp8) && __has_builtin(__builtin_amdgcn_cvt_pk_fp8_f32)
#define HAS_CVT_FP8 1
#endif
#endif

typedef float v2f_t __attribute__((ext_vector_type(2)));
typedef __attribute__((ext_vector_type(8))) short bf16x8;   // 8 bf16 = 4 VGPRs
typedef __attribute__((ext_vector_type(4))) float f32x4;

__device__ inline unsigned short f2bf(float f) {   // RNE float->bf16
    unsigned int u = __float_as_uint(f);
    u += 0x7fffu + ((u >> 16) & 1u);
    return (unsigned short)(u >> 16);
}

__device__ inline float fp8_dec_byte(int b) {
    int s = (b >> 7) & 1, e = (b >> 3) & 15, m = b & 7;
    float v = (e == 0) ? ldexpf((float)m, -9) : ldexpf((float)(8 + m), e - 10);
    return s ? -v : v;
}
__device__ inline unsigned int fp8_enc(float x) {
    unsigned int u = __float_as_uint(x);
    unsigned int s = u >> 31;
    u &= 0x7fffffffu;
    float a = __uint_as_float(u);
    unsigned int code;
    if (a >= 0.015625f) {
        if (a > 448.0f) code = 0x7E;
        else {
            int exp = (int)(u >> 23) - 127;
            unsigned int mant = u & 0x7fffffu;
            unsigned int keep = mant >> 20;
            unsigned int rest = mant & 0xfffffu;
            code = ((unsigned int)(exp + 7) << 3) | keep;
            unsigned int rnd = (rest > 0x80000u) || (rest == 0x80000u && (code & 1));
            code += rnd;
            if (code > 0x7E) code = 0x7E;
        }
    } else {
        code = (unsigned int)(a * 512.0f + 0.5f);
    }
    return (s << 7) | code;
}

// decode 8 packed fp8 (uint2) into 8 floats
__device__ __forceinline__ void fp8x8_dec(uint2 w, float* v) {
#ifdef HAS_CVT_FP8
    v2f_t l0 = __builtin_amdgcn_cvt_pk_f32_fp8((int)w.x, false);
    v2f_t h0 = __builtin_amdgcn_cvt_pk_f32_fp8((int)w.x, true);
    v2f_t l1 = __builtin_amdgcn_cvt_pk_f32_fp8((int)w.y, false);
    v2f_t h1 = __builtin_amdgcn_cvt_pk_f32_fp8((int)w.y, true);
    v[0] = l0[0]; v[1] = l0[1]; v[2] = h0[0]; v[3] = h0[1];
    v[4] = l1[0]; v[5] = l1[1]; v[6] = h1[0]; v[7] = h1[1];
#else
    v[0] = fp8_dec_byte(w.x & 255);        v[1] = fp8_dec_byte((w.x >> 8) & 255);
    v[2] = fp8_dec_byte((w.x >> 16) & 255); v[3] = fp8_dec_byte(w.x >> 24);
    v[4] = fp8_dec_byte(w.y & 255);        v[5] = fp8_dec_byte((w.y >> 8) & 255);
    v[6] = fp8_dec_byte((w.y >> 16) & 255); v[7] = fp8_dec_byte(w.y >> 24);
#endif
}

// ------- setup: zero tails + graph bounds + BN fold + bf16 W-frag pack + pocket MLP/M -------
__global__ void setup_kernel(int* __restrict__ tails, int ntail,
                             const int* __restrict__ batch, int* __restrict__ gstart,
                             int n, int g,
                             const float* __restrict__ conv0_b, const float* __restrict__ convs_b,
                             const float* __restrict__ gamma, const float* __restrict__ beta,
                             const float* __restrict__ mean, const float* __restrict__ var,
                             float* __restrict__ sc, float* __restrict__ sh,
                             const float* __restrict__ convs_W, unsigned short* __restrict__ Wp,
                             const float* __restrict__ pf, const float* __restrict__ W1,
                             const float* __restrict__ b1, const float* __restrict__ W2,
                             const float* __restrict__ b2, const float* __restrict__ bilW,
                             float* __restrict__ M) {
    int t = threadIdx.x;
    int i = blockIdx.x * 256 + t;
    if (i < ntail * 32) tails[i] = 0;
    if (i < 384) {
        int l = i >> 7, f = i & 127;
        float bias = (l == 0) ? conv0_b[f] : convs_b[(l - 1) * 128 + f];
        float s = gamma[i] * rsqrtf(var[i] + EPSBN);
        sc[i] = s;
        sh[i] = fmaf(s, bias - mean[i], beta[i]);
    }
    // pack convs_W (2 layers of 128x128) into MFMA B-fragment order, bf16.
    // frag addr: ((kk*8 + nt)*64 + lane)*8 + j  ->  W[kk*32 + (lane>>4)*8 + j][nt*16 + (lane&15)]
    if (i < 32768) {
        int l = i >> 14;
        int fidx = i & 16383;
        int j  = fidx & 7;
        int ln = (fidx >> 3) & 63;
        int nt = (fidx >> 9) & 7;
        int kk = fidx >> 12;
        int k = kk * 32 + (ln >> 4) * 8 + j;
        int c = nt * 16 + (ln & 15);
        Wp[i] = f2bf(convs_W[l * 16384 + k * 128 + c]);
    }
    if (i < n) {
        int b = batch[i];
        int bp = (i == 0) ? -1 : batch[i - 1];
        for (int q = bp + 1; q <= b; ++q) gstart[q] = i;
        if (i == n - 1) {
            for (int q = b + 1; q <= g; ++q) gstart[q] = n;
        }
    }
    // absorbed pk_bilM (blocks 0..31 compute M = bilW . pk)
    if (blockIdx.x < 32) {
        __shared__ float h1s[64];
        __shared__ float spk[64];
        if (t < 64) {
            float acc = b1[t];
            #pragma unroll
            for (int k = 0; k < 28; ++k) acc = fmaf(pf[k], W1[k * 64 + t], acc);
            h1s[t] = fmaxf(acc, 0.f);
        }
        __syncthreads();
        if (t < 64) {
            float acc2 = b2[t];
            for (int k = 0; k < 64; ++k) acc2 = fmaf(h1s[k], W2[k * 64 + t], acc2);
            spk[t] = acc2;
        }
        __syncthreads();
        if (i < 64 * 128) {
            const float* wr = bilW + (size_t)i * 64;
            float acc = 0.f;
            #pragma unroll 8
            for (int j = 0; j < 64; ++j) acc = fmaf(wr[j], spk[j], acc);
            M[i] = acc;
        }
    }
}

// ---------------- bucket edges by dst window (d>>8) via LDS staging ----------------
__launch_bounds__(256)
__global__ void bucket_kernel(const int* __restrict__ src, const int* __restrict__ dst,
                              unsigned int* __restrict__ buckets, int* __restrict__ tails,
                              unsigned int* __restrict__ ovf, int e, int nwq) {
    __shared__ unsigned int buf[256 * INS_STRIDE];
    __shared__ int cnt[256];
    __shared__ int basee[256];
    int t = threadIdx.x;
    cnt[t] = 0;
    __syncthreads();
    int c0 = blockIdx.x * 2048;
    int c1 = min(c0 + 2048, e);
    for (int i = c0 + t; i < c1; i += 256) {
        int d = dst[i];
        int bb = d >> 8;
        unsigned int val = (unsigned int)src[i] | ((unsigned int)d << 16);
        int pos = atomicAdd(&cnt[bb], 1);
        if (pos < INS_CAP) buf[bb * INS_STRIDE + pos] = val;
        else {
            int op = atomicAdd(&tails[nwq * 32], 1);
            if (op < OVCAP) ovf[op] = val;
        }
    }
    __syncthreads();
    int lane = t & 63, wv = t >> 6;
    int bb0 = wv * 64;
    {
        int b = bb0 + lane;
        int c = (b < nwq) ? min(cnt[b], INS_CAP) : 0;
        basee[b] = c ? atomicAdd(&tails[b * 32], c) : 0;
    }
    for (int k = 0; k < 64; ++k) {
        int b = bb0 + k;
        if (b >= nwq) break;
        int c = min(cnt[b], INS_CAP);
        if (c == 0) continue;
        int g = basee[b];
        if (lane < c) {
            unsigned int v = buf[b * INS_STRIDE + lane];
            int gp = g + lane;
            if (gp < BCAP) buckets[(size_t)b * BCAP + gp] = v;
            else {
                int op = atomicAdd(&tails[nwq * 32], 1);
                if (op < OVCAP) ovf[op] = v;
            }
        }
    }
}

// ---------------- build CSR window-locally in LDS; coalesced write-out ----------------
// Also writes xs = dinv .* x  (pre-scaled node features for the layer-0 gather).
__launch_bounds__(256)
__global__ void build_csr(const unsigned int* __restrict__ buckets,
                          const int* __restrict__ tails, const unsigned int* __restrict__ ovf,
                          unsigned short* __restrict__ csr, int* __restrict__ deg,
                          int* __restrict__ offs, float* __restrict__ dinv,
                          const float* __restrict__ x, float* __restrict__ xs,
                          int n, int nwq) {
    __shared__ unsigned short csrL[CSRL_CAP];
    __shared__ int degL[256], curL[256], offsL[256], cntW[256];
    __shared__ int wsum4[4];
    __shared__ int wstart;
    int b = blockIdx.x, t = threadIdx.x;
    int lo = b << 8;
    int hi = min(lo + 256, n);
    int nw = hi - lo;
    int ovn = min(tails[nwq * 32], OVCAP);
    cntW[t] = (t < nwq) ? min(tails[t * 32], BCAP) : 0;
    degL[t] = 0;
    __syncthreads();
    for (int i = t; i < ovn; i += 256)
        atomicAdd(&cntW[(ovf[i] >> 16) >> 8], 1);
    __syncthreads();
    if (t == 0) {
        int s = 0;
        for (int w = 0; w < b; ++w) s += cntW[w];
        wstart = s;
    }
    int myvalid = min(tails[b * 32], BCAP);
    const unsigned int* myb = buckets + (size_t)b * BCAP;
    for (int i = t; i < myvalid; i += 256)
        atomicAdd(&degL[(myb[i] >> 16) & 255], 1);
    for (int i = t; i < ovn; i += 256) {
        unsigned int v = ovf[i];
        int d = v >> 16;
        if (d >= lo && d < hi) atomicAdd(&degL[d & 255], 1);
    }
    __syncthreads();
    {
        int lane = t & 63, wv = t >> 6;
        int v = degL[t];
        int sc0 = v;
        #pragma unroll
        for (int o = 1; o < 64; o <<= 1) {
            int u = __shfl_up(sc0, o);
            if (lane >= o) sc0 += u;
        }
        if (lane == 63) wsum4[wv] = sc0;
        __syncthreads();
        int wb = 0;
        for (int q = 0; q < wv; ++q) wb += wsum4[q];
        offsL[t] = wb + sc0 - v;
        curL[t] = offsL[t];
    }
    __syncthreads();
    for (int i = t; i < myvalid; i += 256) {
        unsigned int v = myb[i];
        int pos = atomicAdd(&curL[(v >> 16) & 255], 1);
        if (pos < CSRL_CAP) csrL[pos] = (unsigned short)(v & 0xffffu);
    }
    for (int i = t; i < ovn; i += 256) {
        unsigned int v = ovf[i];
        int d = v >> 16;
        if (d >= lo && d < hi) {
            int pos = atomicAdd(&curL[d & 255], 1);
            if (pos < CSRL_CAP) csrL[pos] = (unsigned short)(v & 0xffffu);
        }
    }
    __syncthreads();
    int base = wstart;
    int total = min(cntW[b], CSRL_CAP);
    for (int i = t; i < total; i += 256)
        csr[base + i] = csrL[i];
    if (t < nw) {
        int dgi = degL[t];
        deg[lo + t] = dgi;
        offs[lo + t] = base + offsL[t];
        float dv_ = rsqrtf((float)dgi + 1.0f);
        dinv[lo + t] = dv_;
        #pragma unroll
        for (int k = 0; k < 7; ++k)
            xs[(size_t)(lo + t) * 7 + k] = dv_ * x[(size_t)(lo + t) * 7 + k];
    }
}

// ------- fused dense 128->128 (MFMA bf16) + 8*dinv prescale + fp8-encode + store -------
// hL: [16][136] bf16 rows; Wp pre-packed B-fragments.
// Output row = 8*dinv[node]*(W.h)[node]; the x8 (exact pow2) keeps values in fp8
// normal range (consumer divides by 8).
__device__ __forceinline__ void dense_fp8_out(const unsigned short* hL,
                                              const unsigned short* __restrict__ Wp,
                                              const float* __restrict__ dinv,
                                              unsigned char* __restrict__ out8,
                                              int b0n, int n, int lane, int wv) {
    f32x4 acc0 = {0.f, 0.f, 0.f, 0.f};
    f32x4 acc1 = {0.f, 0.f, 0.f, 0.f};
    int r = lane & 15, g = lane >> 4;
    int nt0 = wv * 2, nt1 = nt0 + 1;
    #pragma unroll
    for (int kk = 0; kk < 4; ++kk) {
        bf16x8 a  = *(const bf16x8*)(hL + r * 136 + kk * 32 + g * 8);
        bf16x8 b0 = *(const bf16x8*)(Wp + ((kk * 8 + nt0) * 64 + lane) * 8);
        bf16x8 b1 = *(const bf16x8*)(Wp + ((kk * 8 + nt1) * 64 + lane) * 8);
        acc0 = __builtin_amdgcn_mfma_f32_16x16x32_bf16(a, b0, acc0, 0, 0, 0);
        acc1 = __builtin_amdgcn_mfma_f32_16x16x32_bf16(a, b1, acc1, 0, 0, 0);
    }
    #pragma unroll
    for (int j = 0; j < 4; ++j) {
        int node = b0n + g * 4 + j;
        if (node < n) {
            float dj = dinv[node] * 8.f;
            float s0 = acc0[j] * dj, s1 = acc1[j] * dj;
            unsigned char q0, q1;
#ifdef HAS_CVT_FP8
            q0 = (unsigned char)(__builtin_amdgcn_cvt_pk_fp8_f32(s0, s0, 0, false) & 0xff);
            q1 = (unsigned char)(__builtin_amdgcn_cvt_pk_fp8_f32(s1, s1, 0, false) & 0xff);
#else
            q0 = (unsigned char)fp8_enc(s0);
            q1 = (unsigned char)fp8_enc(s1);
#endif
            out8[(size_t)node * 128 + nt0 * 16 + r] = q0;
            out8[(size_t)node * 128 + nt1 * 16 + r] = q1;
        }
    }
}

// ------- fused layer-0: agg(xs) 7-dim + dense 7->128 + BN + relu + dense W1 -> fp8 -------
// Neighbor gather reads pre-scaled xs (= dinv.*x): no dinv gather, no weight shuffle.
__launch_bounds__(256)
__global__ void layer0f_kernel(const float* __restrict__ x, const float* __restrict__ xs,
                               const unsigned short* __restrict__ csr,
                               const int* __restrict__ offs, const int* __restrict__ degi,
                               const float* __restrict__ dinv, const float* __restrict__ W,
                               const float* __restrict__ sc, const float* __restrict__ sh,
                               const unsigned short* __restrict__ Wp,
                               unsigned char* __restrict__ out8, int n) {
    __shared__ float sW[7 * 128];
    __shared__ float ssc[128], ssh[128];
    __shared__ unsigned short hL[16 * 136];
    int t = threadIdx.x;
    for (int i = t; i < 7 * 128; i += 256) sW[i] = W[i];
    if (t < 128) { ssc[t] = sc[t]; ssh[t] = sh[t]; }
    __syncthreads();
    int lane = t & 63, wv = t >> 6;
    int b0n = blockIdx.x * 16;
    int e = lane >> 3, f = lane & 7;
    for (int nd = 0; nd < 4; ++nd) {
        int node = b0n + wv * 4 + nd;
        if (node < n) {
            int off = offs[node], cnt = degi[node];
            float di = dinv[node];
            float acc = 0.f, accB = 0.f;
            for (int b0 = 0; b0 < cnt; b0 += 64) {
                int j = b0 + lane;
                int s = 0;
                if (j < cnt) s = csr[off + j];
                int m = cnt - b0; if (m > 64) m = 64;
                int m16 = (m + 15) & ~15;
                for (int i2 = 0; i2 < m16; i2 += 16) {
                    int ss1 = __shfl(s, i2 + e);
                    int ss2 = __shfl(s, i2 + 8 + e);
                    float nn1 = (i2 + e < m) ? 1.f : 0.f;
                    float nn2 = (i2 + 8 + e < m) ? 1.f : 0.f;
                    float v1 = 0.f, v2 = 0.f;
                    if (f < 7) {
                        v1 = xs[(size_t)ss1 * 7 + f];
                        v2 = xs[(size_t)ss2 * 7 + f];
                    }
                    acc  = fmaf(nn1, v1, acc);
                    accB = fmaf(nn2, v2, accB);
                }
            }
            acc += accB;
            acc += __shfl_xor(acc, 8);
            acc += __shfl_xor(acc, 16);
            acc += __shfl_xor(acc, 32);
            float self = (f < 7) ? x[(size_t)node * 7 + f] : 0.f;
            float xa = di * (acc + di * self);
            float xk[7];
            #pragma unroll
            for (int k = 0; k < 7; ++k) xk[k] = __shfl(xa, k);
            int fo = lane * 2;
            float o0 = 0.f, o1 = 0.f;
            #pragma unroll
            for (int k = 0; k < 7; ++k) {
                o0 = fmaf(xk[k], sW[k * 128 + fo], o0);
                o1 = fmaf(xk[k], sW[k * 128 + fo + 1], o1);
            }
            o0 = fmaxf(fmaf(ssc[fo],     o0, ssh[fo]),     0.f);
            o1 = fmaxf(fmaf(ssc[fo + 1], o1, ssh[fo + 1]), 0.f);
            unsigned int p = (unsigned int)f2bf(o0) | ((unsigned int)f2bf(o1) << 16);
            *(unsigned int*)(&hL[(wv * 4 + nd) * 136 + fo]) = p;
        }
    }
    __syncthreads();
    dense_fp8_out(hL, Wp, dinv, out8, b0n, n, lane, wv);
}

// ------- fused aggregation over PRE-SCALED fp8 table + foldedBN + ReLU (+ dense -> fp8) -----
// Table rows are 8*dinv[s]*(W.h)[s]: aggregation = masked row-sum (no dinv gather).
// Self term: table[node] = 8*di*h[node]  =>  agg_total = (sum + table[node]) * di/8.
// TWO NODES PER WAVE processed concurrently: 8 independent row-gathers in flight
// (vs 4) to double per-wave memory-level parallelism. Per-node arithmetic order
// is unchanged (bitwise-identical results).
// DENSE=1: writes next layer's scaled fp8 table via MFMA; DENSE=0: writes bf16 h3.
template<int DENSE>
__launch_bounds__(256)
__global__ void aggf_kernel(const unsigned int* __restrict__ hw, const unsigned short* __restrict__ csr,
                            const int* __restrict__ offs, const int* __restrict__ degi,
                            const float* __restrict__ dinv,
                            const float* __restrict__ sc, const float* __restrict__ shv,
                            const unsigned short* __restrict__ Wp,
                            unsigned char* __restrict__ out8,
                            unsigned int* __restrict__ outH2, int n) {
    __shared__ unsigned short hL[16 * 136];
    int t = threadIdx.x, lane = t & 63, wv = t >> 6;
    int fl = lane & 15, grp = lane >> 4;
    int b0n = blockIdx.x * 16;
    for (int np = 0; np < 2; ++np) {
        int nodeA = b0n + wv * 4 + np * 2;
        int nodeB = nodeA + 1;
        bool okA = nodeA < n, okB = nodeB < n;
        int offA = okA ? offs[nodeA] : 0;
        int cntA = okA ? degi[nodeA] : 0;
        int offB = okB ? offs[nodeB] : 0;
        int cntB = okB ? degi[nodeB] : 0;
        float diA = okA ? dinv[nodeA] : 0.f;
        float diB = okB ? dinv[nodeB] : 0.f;
        float aA[8], aB[8];
        #pragma unroll
        for (int i = 0; i < 8; ++i) { aA[i] = 0.f; aB[i] = 0.f; }
        int cmax = max(cntA, cntB);
        for (int c0 = 0; c0 < cmax; c0 += 64) {
            int j = c0 + lane;
            int sA = (j < cntA) ? csr[offA + j] : 0;
            int sB = (j < cntB) ? csr[offB + j] : 0;
            int mA = cntA - c0; mA = (mA < 0) ? 0 : ((mA > 64) ? 64 : mA);
            int mB = cntB - c0; mB = (mB < 0) ? 0 : ((mB > 64) ? 64 : mB);
            int mm = (mA > mB) ? mA : mB;
            int m16 = (mm + 15) & ~15;
            for (int e = 0; e < m16; e += 16) {
                uint2 wA[4], wB[4];
                #pragma unroll
                for (int u = 0; u < 4; ++u) {
                    int jj = e + u * 4 + grp;
                    int ssA = __shfl(sA, jj);
                    int ssB = __shfl(sB, jj);
                    wA[u] = *(const uint2*)(hw + (size_t)ssA * 32 + fl * 2);
                    wB[u] = *(const uint2*)(hw + (size_t)ssB * 32 + fl * 2);
                }
                #pragma unroll
                for (int u = 0; u < 4; ++u) {
                    int jj = e + u * 4 + grp;
                    float nnA = (jj < mA) ? 1.f : 0.f;
                    float nnB = (jj < mB) ? 1.f : 0.f;
                    float v[8];
                    fp8x8_dec(wA[u], v);
                    #pragma unroll
                    for (int i = 0; i < 8; ++i) aA[i] = fmaf(nnA, v[i], aA[i]);
                    fp8x8_dec(wB[u], v);
                    #pragma unroll
                    for (int i = 0; i < 8; ++i) aB[i] = fmaf(nnB, v[i], aB[i]);
                }
            }
        }
        #pragma unroll
        for (int i = 0; i < 8; ++i) {
            aA[i] += __shfl_xor(aA[i], 16);
            aA[i] += __shfl_xor(aA[i], 32);
            aB[i] += __shfl_xor(aB[i], 16);
            aB[i] += __shfl_xor(aB[i], 32);
        }
        if (grp == 0) {
            #pragma unroll
            for (int half = 0; half < 2; ++half) {
                int node = (half == 0) ? nodeA : nodeB;
                bool ok  = (half == 0) ? okA : okB;
                float di = (half == 0) ? diA : diB;
                float* a = (half == 0) ? aA : aB;
                if (ok) {
                    uint2 ws = *(const uint2*)(hw + (size_t)node * 32 + fl * 2);
                    float sv[8];
                    fp8x8_dec(ws, sv);
                    int f0 = fl * 8;
                    float dis = di * 0.125f;   // undo the x8 table prescale (exact pow2)
                    float vo[8];
                    #pragma unroll
                    for (int i = 0; i < 8; ++i) {
                        float vv = (a[i] + sv[i]) * dis;
                        vo[i] = fmaxf(fmaf(sc[f0 + i], vv, shv[f0 + i]), 0.f);
                    }
                    uint4 P;
                    P.x = (unsigned int)f2bf(vo[0]) | ((unsigned int)f2bf(vo[1]) << 16);
                    P.y = (unsigned int)f2bf(vo[2]) | ((unsigned int)f2bf(vo[3]) << 16);
                    P.z = (unsigned int)f2bf(vo[4]) | ((unsigned int)f2bf(vo[5]) << 16);
                    P.w = (unsigned int)f2bf(vo[6]) | ((unsigned int)f2bf(vo[7]) << 16);
                    if (DENSE) {
                        *(uint4*)(&hL[(wv * 4 + np * 2 + half) * 136 + f0]) = P;
                    } else {
                        *(uint4*)(outH2 + (size_t)node * 64 + fl * 4) = P;
                    }
                }
            }
        }
    }
    if (DENSE) {
        __syncthreads();
        dense_fp8_out(hL, Wp, dinv, out8, b0n, n, lane, wv);
    }
}

// ------- per-graph tail (segment-mean over bf16 h3 + bilinear + classifier), 256 thr -------
__launch_bounds__(256)
__global__ void final_kernel(const unsigned int* __restrict__ h2, const int* __restrict__ gstart,
                             const float* __restrict__ M, const float* __restrict__ bil_b,
                             const float* __restrict__ cW1, const float* __restrict__ cb1,
                             const float* __restrict__ cW2, const float* __restrict__ cb2,
                             float* __restrict__ out) {
    __shared__ float lig4[4][128];
    __shared__ float lig[128];
    __shared__ float inter[64];
    __shared__ float hc[32];
    int g = blockIdx.x, t = threadIdx.x;
    int grp = t >> 6, tid = t & 63;
    int s = gstart[g], e = gstart[g + 1];
    float a0 = 0.f, a1 = 0.f, b0 = 0.f, b1 = 0.f;
    int i = s + grp;
    for (; i + 4 < e; i += 8) {
        unsigned int u0 = h2[(size_t)i * 64 + tid];
        unsigned int u1 = h2[(size_t)(i + 4) * 64 + tid];
        a0 += __uint_as_float(u0 << 16);
        a1 += __uint_as_float(u0 & 0xffff0000u);
        b0 += __uint_as_float(u1 << 16);
        b1 += __uint_as_float(u1 & 0xffff0000u);
    }
    for (; i < e; i += 4) {
        unsigned int u0 = h2[(size_t)i * 64 + tid];
        a0 += __uint_as_float(u0 << 16);
        a1 += __uint_as_float(u0 & 0xffff0000u);
    }
    lig4[grp][tid * 2]     = a0 + b0;
    lig4[grp][tid * 2 + 1] = a1 + b1;
    __syncthreads();
    if (t < 128) {
        float c = (float)(e - s); if (c < 1.f) c = 1.f;
        lig[t] = ((lig4[0][t] + lig4[1][t]) + (lig4[2][t] + lig4[3][t])) / c;
    }
    __syncthreads();
    if (t < 64) {
        float acc = bil_b[t];
        const float* mr = M + (size_t)t * 128;
        #pragma unroll 8
        for (int k = 0; k < 128; ++k) acc = fmaf(lig[k], mr[k], acc);
        inter[t] = acc;
    }
    __syncthreads();
    if (t < 32) {
        float acc = cb1[t];
        #pragma unroll 8
        for (int o = 0; o < 64; ++o) acc = fmaf(inter[o], cW1[o * 32 + t], acc);
        hc[t] = fmaxf(acc, 0.f);
    }
    __syncthreads();
    if (t == 0) {
        float acc = cb2[0];
        #pragma unroll
        for (int j = 0; j < 32; ++j) acc = fmaf(hc[j], cW2[j], acc);
        out[g] = acc;
    }
}

extern "C" void kernel_launch(void* const* d_in, const int* in_sizes, int n_in,
                              void* d_out, int out_size, void* d_ws, size_t ws_size,
                              hipStream_t stream) {
    const float* x        = (const float*)d_in[0];
    const int*   edge     = (const int*)d_in[1];
    const int*   batch    = (const int*)d_in[2];
    const float* pocket   = (const float*)d_in[3];
    const float* conv0_W  = (const float*)d_in[4];
    const float* conv0_b  = (const float*)d_in[5];
    const float* convs_W  = (const float*)d_in[6];
    const float* convs_b  = (const float*)d_in[7];
    const float* bn_gamma = (const float*)d_in[8];
    const float* bn_beta  = (const float*)d_in[9];
    const float* bn_mean  = (const float*)d_in[10];
    const float* bn_var   = (const float*)d_in[11];
    const float* pmlp_W1  = (const float*)d_in[12];
    const float* pmlp_b1  = (const float*)d_in[13];
    const float* pmlp_W2  = (const float*)d_in[14];
    const float* pmlp_b2  = (const float*)d_in[15];
    const float* bil_W    = (const float*)d_in[16];
    const float* bil_b    = (const float*)d_in[17];
    const float* cls_W1   = (const float*)d_in[18];
    const float* cls_b1   = (const float*)d_in[19];
    const float* cls_W2   = (const float*)d_in[20];
    const float* cls_b2   = (const float*)d_in[21];

    const int N = in_sizes[0] / 7;
    const int E = in_sizes[1] / 2;
    const int G = out_size;
    const int* srcA = edge;
    const int* dstA = edge + E;
    const int NB  = (N + 255) / 256;
    const int NWQ = (N + 255) >> 8;
    const int NBL = (N + 15) / 16;

    char* p = (char*)d_ws;
    auto alloc = [&](size_t bytes) -> void* {
        void* r = (void*)p;
        p += (bytes + 255) & ~(size_t)255;
        return r;
    };
    int*   tails    = (int*)alloc((size_t)(NWQ + 1) * 32 * 4);
    unsigned int* buckets = (unsigned int*)alloc((size_t)NWQ * BCAP * 4);
    unsigned int* ovf     = (unsigned int*)alloc((size_t)OVCAP * 4);
    int*   deg      = (int*)alloc((size_t)N * 4);
    int*   offs     = (int*)alloc((size_t)N * 4);
    float* dinv     = (float*)alloc((size_t)N * 4);
    float* xs       = (float*)alloc((size_t)N * 7 * 4);
    unsigned short* csr = (unsigned short*)alloc((size_t)E * 2);
    unsigned char* bufH8a = (unsigned char*)alloc((size_t)N * 128);
    unsigned char* bufH8b = (unsigned char*)alloc((size_t)N * 128);
    unsigned int* bufH2 = (unsigned int*)alloc((size_t)N * 64 * 4);   // bf16 h3, 2 feats/uint
    int*   gstart   = (int*)alloc((size_t)(G + 1) * 4);
    float* M        = (float*)alloc(64 * 128 * 4);
    float* sc       = (float*)alloc(384 * 4);
    float* shv      = (float*)alloc(384 * 4);
    unsigned short* Wp = (unsigned short*)alloc((size_t)2 * 16384 * 2);

    setup_kernel<<<NB, 256, 0, stream>>>(tails, NWQ + 1, batch, gstart, N, G,
                                         conv0_b, convs_b, bn_gamma, bn_beta, bn_mean, bn_var,
                                         sc, shv, convs_W, Wp,
                                         pocket, pmlp_W1, pmlp_b1, pmlp_W2, pmlp_b2, bil_W, M);
    bucket_kernel<<<(E + 2047) / 2048, 256, 0, stream>>>(srcA, dstA, buckets, tails, ovf,
                                                         E, NWQ);
    build_csr<<<NWQ, 256, 0, stream>>>(buckets, tails, ovf, csr, deg, offs, dinv,
                                       x, xs, N, NWQ);

    // layer 0 fused: agg(xs) + W0 + BN + relu + W1(MFMA) -> scaled fp8 table1
    layer0f_kernel<<<NBL, 256, 0, stream>>>(x, xs, csr, offs, deg, dinv, conv0_W,
                                            sc, shv, Wp, bufH8a, N);
    // layer 1 fused: agg(table1) + BN + relu + W2(MFMA) -> scaled fp8 table2
    aggf_kernel<1><<<NBL, 256, 0, stream>>>((const unsigned int*)bufH8a, csr, offs, deg, dinv,
                                            sc + 128, shv + 128, Wp + 16384, bufH8b, nullptr, N);
    // layer 2: agg(table2) + BN + relu -> bf16 h3
    aggf_kernel<0><<<NBL, 256, 0, stream>>>((const unsigned int*)bufH8b, csr, offs, deg, dinv,
                                            sc + 256, shv + 256, nullptr, nullptr, bufH2, N);

    final_kernel<<<G, 256, 0, stream>>>(bufH2, gstart, M, bil_b, cls_W1, cls_b1, cls_W2, cls_b2,
                                        (float*)d_out);
}